// Round 3
// baseline (720.199 us; speedup 1.0000x reference)
//
#include <hip/hip_runtime.h>
#include <hip/hip_bf16.h>

// AngularMarginLoss: B=2048, D=256, C=100000
// loss = -mean_b( num_b - log(exp(num_b) + sum_{c!=t_b} exp(30*cos_bc) + 1e-6) )
// num_b = 30*cos(acos(clip(cos_bt)) + 0.2)
//
// Round-11: resident parallelism was capped at ~1.5 blocks/CU (occupancy
// 18.5% despite 5-block LDS limit) -> waves/CU ~6, so MFMA (42us/CU) and
// VALU (38us/CU) never overlapped (35%+29% busy, 36% idle). Lever: waves
// per BLOCK instead of blocks.
//  * 512-thr blocks (8 waves), 1 slice/block, 16 tiles/wave. Even at the
//    observed ~2-blocks/CU cap this gives 16 waves/CU (50% occ).
//    __launch_bounds__(512,4) pins VGPR <= 128 (the 16-waves/CU boundary).
//  * One-pass 8-wave prologue: thread = (row, ks) split, 32 contiguous
//    floats held in regs, 3-level shfl norm, 4 bf16x8 LDS writes. W read
//    ONCE (was 2 passes).
//  * Tail: only the xor-32 shfl reduce; store 32 partials/tile (128B
//    coalesced). k_finish sums the extra 2x (25.6MB, 64 blocks).
//  * b0 prefetch issued before prologue (hides under W loads).

static constexpr int Bn = 2048;
static constexpr int Dn = 256;
static constexpr int Cn = 100000;
static constexpr int NSLICE = 1564;                 // 64-col slices
static constexpr int CPAD   = NSLICE * 64;          // 100096
static constexpr float OOB_COLS = (float)(CPAD - Cn);   // 96 (exp2(0)=1 each)
static constexpr int NT  = Bn / 16;                 // 128 sample tiles
static constexpr int NWV = 8;                       // waves per block
static constexpr int NTW = NT / NWV;                // 16 tiles per wave

#define SCALE_F 30.0f
#define MARGIN_F 0.2f
#define EPS_F 1e-6f
#define L2E_SCALE 43.2808512266689f   /* 30 * log2(e): exp(30*c) = 2^(L2E*c) */

typedef __attribute__((ext_vector_type(8))) short bf16x8;   // 8 bf16 = 4 VGPRs
typedef __attribute__((ext_vector_type(4))) float f32x4;

__device__ __forceinline__ short f2bf_rne(float x) {
    union { float f; unsigned int u; } v; v.f = x;
    unsigned int r = v.u + 0x7fffu + ((v.u >> 16) & 1u);
    return (short)(r >> 16);
}

// ---- kernel 1: fused prep ----
// blocks [0,256)    : pack emb fp32 -> embF (bf16, MFMA B-fragment order),
//                     PRE-SCALED by 30*log2(e) so k_main's exp is a bare v_exp.
//   chunk (t,ks,lane): embF[((t*8+ks)*64+lane)*8 .. +7] = bf16 of
//   L2E * emb[t*16 + (lane&15)][ks*32 + (lane>>4)*8 + j], j=0..7
// blocks [256,768)  : per-sample target cosine -> numv, etv (exact fp32 path)
__global__ __launch_bounds__(256) void k_prep(const float* __restrict__ W,
                                              const float* __restrict__ emb,
                                              const int* __restrict__ tgt,
                                              short* __restrict__ embF,
                                              float* __restrict__ numv,
                                              float* __restrict__ etv) {
    const int blk = blockIdx.x;
    if (blk < 256) {
        const int t     = blk >> 1;
        const int chunk = (blk & 1) * 256 + threadIdx.x;   // [0,512)
        const int ks    = chunk >> 6;
        const int lane  = chunk & 63;
        const int q     = lane >> 4;
        const int cr    = lane & 15;
        const float* src = emb + (size_t)(t * 16 + cr) * Dn + ks * 32 + q * 8;
        float4 x0 = *(const float4*)(src);
        float4 x1 = *(const float4*)(src + 4);
        bf16x8 o;
        o[0] = f2bf_rne(x0.x * L2E_SCALE); o[1] = f2bf_rne(x0.y * L2E_SCALE);
        o[2] = f2bf_rne(x0.z * L2E_SCALE); o[3] = f2bf_rne(x0.w * L2E_SCALE);
        o[4] = f2bf_rne(x1.x * L2E_SCALE); o[5] = f2bf_rne(x1.y * L2E_SCALE);
        o[6] = f2bf_rne(x1.z * L2E_SCALE); o[7] = f2bf_rne(x1.w * L2E_SCALE);
        *(bf16x8*)(embF + (size_t)((t * 8 + ks) * 64 + lane) * 8) = o;
    } else {
        const int b    = (blk - 256) * 4 + (threadIdx.x >> 6);
        const int lane = threadIdx.x & 63;
        const int t    = tgt[b];
        float4 x = *(const float4*)(W + (size_t)t * Dn + lane * 4);
        float4 e = *(const float4*)(emb + b * Dn + lane * 4);
        float dot = x.x * e.x + x.y * e.y + x.z * e.z + x.w * e.w;
        float ss  = x.x * x.x + x.y * x.y + x.z * x.z + x.w * x.w;
#pragma unroll
        for (int o = 1; o < 64; o <<= 1) {
            dot += __shfl_xor(dot, o);
            ss  += __shfl_xor(ss, o);
        }
        if (lane == 0) {
            float cosv = dot / fmaxf(sqrtf(ss), 1e-12f);
            cosv = fminf(fmaxf(cosv, -1.f), 1.f);
            const float num = SCALE_F * cosf(acosf(cosv) + MARGIN_F);
            numv[b] = num;
            etv[b]  = __expf(SCALE_F * cosv);
        }
    }
}

// ---- kernel 2: main fused GEMM + exp row-sum ----
// Block = one 64-col slice, 8 waves (512 thr). One-pass cooperative
// W-normalize into 32KB LDS; then each wave owns 16 sample-tiles,
// barrier-free (waves drift -> pipe phases stagger).
__global__ __launch_bounds__(512, 4) void k_main(const float* __restrict__ W,
                                                 const short* __restrict__ embF,
                                                 float* __restrict__ partial) {
    __shared__ short afrag_sh[4 * 8 * 64 * 8];   // 32 KB, [((ct*8+ks)*64+lane')*8]
    const int tid  = threadIdx.x;
    const int lane = tid & 63;
    const int wv   = tid >> 6;    // wave id 0..7
    const int sl   = blockIdx.x;
    const int cbase = sl * 64;

    const bf16x8* bsrc = (const bf16x8*)embF;   // chunk-indexed (16B units)
    const int t0 = wv * NTW;                    // this wave's sample range

    // B fragments for tile t: chunks t*512 + ks*64 + lane (coalesced 1KB/inst)
    auto load_b = [&](bf16x8* bf, int t) {
        const bf16x8* p = bsrc + (size_t)t * 512 + lane;
#pragma unroll
        for (int ks = 0; ks < 8; ++ks) bf[ks] = p[ks * 64];
    };

    bf16x8 b0[8], b1[8];
    load_b(b0, t0);   // issue before prologue: latency hides under W loads

    // ---- one-pass prologue: thread = (row rlo = wv*8 + lane>>3, ks = lane&7)
    // holds W[c][ks*32 .. +32) in regs; 3-level shfl for the row norm; writes
    // fragment chunks (ct=rlo>>4, ks) at lanes' q*16 + (rlo&15), q=0..3.
    {
        const int ks  = lane & 7;
        const int rlo = wv * 8 + (lane >> 3);   // row-in-slice 0..63
        const int c   = cbase + rlo;
        const int ct  = rlo >> 4;
        const int crr = rlo & 15;
        float v[32];
        if (c < Cn) {
            const float* wr = W + (size_t)c * Dn + ks * 32;
#pragma unroll
            for (int j = 0; j < 8; ++j) {
                float4 x = *(const float4*)(wr + j * 4);
                v[j * 4 + 0] = x.x; v[j * 4 + 1] = x.y;
                v[j * 4 + 2] = x.z; v[j * 4 + 3] = x.w;
            }
        } else {
#pragma unroll
            for (int j = 0; j < 32; ++j) v[j] = 0.0f;
        }
        float ss = 0.0f;
#pragma unroll
        for (int j = 0; j < 32; ++j) ss += v[j] * v[j];
        ss += __shfl_xor(ss, 1);   // combine the 8 ks-lanes of this row
        ss += __shfl_xor(ss, 2);
        ss += __shfl_xor(ss, 4);
        const float rn = 1.0f / fmaxf(sqrtf(ss), 1e-12f);
#pragma unroll
        for (int q2 = 0; q2 < 4; ++q2) {
            bf16x8 a;
#pragma unroll
            for (int j = 0; j < 8; ++j) a[j] = f2bf_rne(v[q2 * 8 + j] * rn);
            *(bf16x8*)(afrag_sh + (size_t)(((ct * 8 + ks) * 64) + q2 * 16 + crr) * 8) = a;
        }
    }
    __syncthreads();

    float* pout = partial + (size_t)sl * (NT * 32);   // 4096 floats per slice

    auto compute = [&](const bf16x8* bf, int t) {
        f32x4 a0 = {0.f, 0.f, 0.f, 0.f};
        f32x4 a1 = {0.f, 0.f, 0.f, 0.f};
        f32x4 a2 = {0.f, 0.f, 0.f, 0.f};
        f32x4 a3 = {0.f, 0.f, 0.f, 0.f};
#pragma unroll
        for (int ks = 0; ks < 8; ++ks) {
            const short* ap = afrag_sh + (size_t)(ks * 64 + lane) * 8;
            bf16x8 w0 = *(const bf16x8*)(ap);            // ct stride = 4096 shorts
            bf16x8 w1 = *(const bf16x8*)(ap + 4096);
            bf16x8 w2 = *(const bf16x8*)(ap + 8192);
            bf16x8 w3 = *(const bf16x8*)(ap + 12288);
            a0 = __builtin_amdgcn_mfma_f32_16x16x32_bf16(w0, bf[ks], a0, 0, 0, 0);
            a1 = __builtin_amdgcn_mfma_f32_16x16x32_bf16(w1, bf[ks], a1, 0, 0, 0);
            a2 = __builtin_amdgcn_mfma_f32_16x16x32_bf16(w2, bf[ks], a2, 0, 0, 0);
            a3 = __builtin_amdgcn_mfma_f32_16x16x32_bf16(w3, bf[ks], a3, 0, 0, 0);
        }
        // D layout: col=lane&15=sample, row=q*4+reg=class. d = 30*log2e*cos,
        // so exp(30*cos) = exp2(d): one v_exp_f32, no mul.
        float s0 = 0.f, s1 = 0.f, s2 = 0.f, s3 = 0.f;
#pragma unroll
        for (int r = 0; r < 4; ++r) {
            s0 += __builtin_amdgcn_exp2f(a0[r]);
            s1 += __builtin_amdgcn_exp2f(a1[r]);
            s2 += __builtin_amdgcn_exp2f(a2[r]);
            s3 += __builtin_amdgcn_exp2f(a3[r]);
        }
        float s = (s0 + s1) + (s2 + s3);
        s += __shfl_xor(s, 32);                  // halve: only one cross-lane op
        if (lane < 32) pout[t * 32 + lane] = s;  // 128B coalesced, 2 partials/sample
    };

    for (int i = 0; i < NTW; i += 2) {
        load_b(b1, t0 + i + 1);                          // ~1 tile ahead of use
        compute(b0, t0 + i);
        load_b(b0, (i + 2) < NTW ? (t0 + i + 2) : t0);   // overrun-clamped
        compute(b1, t0 + i + 1);
    }
}

// ---- kernel 3: fused rowsum + loss ----
// 64 blocks x 256 thr; block owns 32 samples. Work items (sl, half):
// 1564*2 = 3128 = 8*391, split across 8 chunks of threads.
__global__ __launch_bounds__(256) void k_finish(const float* __restrict__ partial,
                                                const float* __restrict__ numv,
                                                const float* __restrict__ etv,
                                                float* __restrict__ out) {
    __shared__ float red[32];
    const int l     = threadIdx.x & 31;          // sample within block
    const int chunk = threadIdx.x >> 5;          // 0..7
    const int b  = blockIdx.x * 32 + l;
    const int t  = b >> 4;
    const int cr = b & 15;

    if (threadIdx.x < 32) red[threadIdx.x] = 0.0f;
    __syncthreads();

    float acc = 0.0f;
    const int i0 = chunk * 391, i1 = i0 + 391;
    for (int idx = i0; idx < i1; ++idx) {
        const int s = idx >> 1, h = idx & 1;
        acc += partial[(size_t)s * (NT * 32) + t * 32 + h * 16 + cr];
    }
    acc += __shfl_xor(acc, 32);                  // merge lane pairs (chunk 2w/2w+1)
    if ((threadIdx.x & 63) < 32) atomicAdd(&red[l], acc);
    __syncthreads();

    if (threadIdx.x < 32) {
        const int bb = blockIdx.x * 32 + threadIdx.x;
        const float num  = numv[bb];
        const float excl = red[threadIdx.x] - OOB_COLS - etv[bb];  // drop pad + target
        float term = num - logf(__expf(num) + excl + EPS_F);
#pragma unroll
        for (int o = 1; o < 32; o <<= 1) term += __shfl_xor(term, o);
        if (threadIdx.x == 0) atomicAdd(out, -term / (float)Bn);
    }
}

extern "C" void kernel_launch(void* const* d_in, const int* in_sizes, int n_in,
                              void* d_out, int out_size, void* d_ws, size_t ws_size,
                              hipStream_t stream) {
    const float* emb = (const float*)d_in[0];   // 2048*256
    const float* W   = (const float*)d_in[1];   // 100000*256
    const int*   tgt = (const int*)d_in[2];     // 2048
    float* out = (float*)d_out;

    char* ws = (char*)d_ws;
    short* embF    = (short*)ws;                             // 1 MB (fragment order)
    float* partial = (float*)(ws + (1 << 20));               // 1564*4096*4 = 25.6 MB
    float* numv    = partial + (size_t)NSLICE * (NT * 32);   // 8 KB
    float* etv     = numv + Bn;                              // 8 KB

    hipMemsetAsync(out, 0, sizeof(float), stream);
    k_prep<<<768, 256, 0, stream>>>(W, emb, tgt, embF, numv, etv);
    k_main<<<NSLICE, 512, 0, stream>>>(W, embF, partial);
    k_finish<<<64, 256, 0, stream>>>(partial, numv, etv, out);
}

// Round 4
// 324.894 us; speedup vs baseline: 2.2167x; 2.2167x over previous
//
#include <hip/hip_runtime.h>
#include <hip/hip_bf16.h>

// AngularMarginLoss: B=2048, D=256, C=100000
// loss = -mean_b( num_b - log(exp(num_b) + sum_{c!=t_b} exp(30*cos_bc) + 1e-6) )
// num_b = 30*cos(acos(clip(cos_bt)) + 0.2)
//
// Round-12: two lessons applied.
//  * R11 spilled: hipcc reads __launch_bounds__ arg2 as min BLOCKS/CU
//    (4 blocks x 8 waves -> 64 VGPR -> 1.5GB scratch traffic). Now (512,2)
//    -> 128 VGPR, and per-thread state kept ~110 regs (no B ping-pong; 4
//    waves/SIMD TLP hides L2 latency instead of ILP).
//  * R10's 132us was LDS-BW-bound: afrag-from-LDS costs 16B/lane per MFMA
//    = 25.6MB/CU ~ 107-125us at ds_read_b128 rate. Switch to
//    mfma_f32_32x32x16_bf16: one A-frag read feeds 2x the FLOP -> 12.8MB/CU
//    ~ 55-62us, at parity with the 50us/CU MFMA floor.
//  * Prologue: wave wv owns k-chunk [wv*32,+32) of all 64 rows (lane=row);
//    LDS frag writes are lane-contiguous (conflict-free, R11 had 2.8M
//    conflicts); cross-wave row-norm via 2KB ssq + barrier.
//  * embF pre-scaled by 30*log2(e): exp(30*cos) = one v_exp2_f32.

static constexpr int Bn = 2048;
static constexpr int Dn = 256;
static constexpr int Cn = 100000;
static constexpr int NSLICE = 1564;                 // 64-col slices
static constexpr int CPAD   = NSLICE * 64;          // 100096
static constexpr float OOB_COLS = (float)(CPAD - Cn);   // 96 (exp2(0)=1 each)
static constexpr int NT  = Bn / 32;                 // 64 sample tiles (32-wide)
static constexpr int NWV = 8;                       // waves per block
static constexpr int NTW = NT / NWV;                // 8 tiles per wave

#define SCALE_F 30.0f
#define MARGIN_F 0.2f
#define EPS_F 1e-6f
#define L2E_SCALE 43.2808512266689f   /* 30 * log2(e): exp(30*c) = 2^(L2E*c) */

typedef __attribute__((ext_vector_type(8))) short bf16x8;    // 8 bf16 = 4 VGPRs
typedef __attribute__((ext_vector_type(16))) float f32x16;   // 32x32 acc half

__device__ __forceinline__ short f2bf_rne(float x) {
    union { float f; unsigned int u; } v; v.f = x;
    unsigned int r = v.u + 0x7fffu + ((v.u >> 16) & 1u);
    return (short)(r >> 16);
}

// ---- kernel 1: fused prep ----
// blocks [0,256)    : pack emb fp32 -> embF (bf16, 32x32x16 MFMA B-fragment
//                     order), PRE-SCALED by 30*log2(e).
//   chunk (t,ks,lane): embF[((t*16+ks)*64+lane)*8 .. +7] = bf16 of
//   L2E * emb[t*32 + (lane&31)][ks*16 + (lane>>5)*8 + j], j=0..7
// blocks [256,768)  : per-sample target cosine -> numv, etv (exact fp32 path)
__global__ __launch_bounds__(256) void k_prep(const float* __restrict__ W,
                                              const float* __restrict__ emb,
                                              const int* __restrict__ tgt,
                                              short* __restrict__ embF,
                                              float* __restrict__ numv,
                                              float* __restrict__ etv) {
    const int blk = blockIdx.x;
    if (blk < 256) {
        const int t     = blk >> 2;                        // sample tile 0..63
        const int chunk = (blk & 3) * 256 + threadIdx.x;   // [0,1024)
        const int ks    = chunk >> 6;                      // 0..15
        const int lane  = chunk & 63;
        const float* src = emb + (size_t)(t * 32 + (lane & 31)) * Dn
                               + ks * 16 + (lane >> 5) * 8;
        float4 x0 = *(const float4*)(src);
        float4 x1 = *(const float4*)(src + 4);
        bf16x8 o;
        o[0] = f2bf_rne(x0.x * L2E_SCALE); o[1] = f2bf_rne(x0.y * L2E_SCALE);
        o[2] = f2bf_rne(x0.z * L2E_SCALE); o[3] = f2bf_rne(x0.w * L2E_SCALE);
        o[4] = f2bf_rne(x1.x * L2E_SCALE); o[5] = f2bf_rne(x1.y * L2E_SCALE);
        o[6] = f2bf_rne(x1.z * L2E_SCALE); o[7] = f2bf_rne(x1.w * L2E_SCALE);
        *(bf16x8*)(embF + (size_t)((t * 16 + ks) * 64 + lane) * 8) = o;
    } else {
        const int b    = (blk - 256) * 4 + (threadIdx.x >> 6);
        const int lane = threadIdx.x & 63;
        const int t    = tgt[b];
        float4 x = *(const float4*)(W + (size_t)t * Dn + lane * 4);
        float4 e = *(const float4*)(emb + b * Dn + lane * 4);
        float dot = x.x * e.x + x.y * e.y + x.z * e.z + x.w * e.w;
        float ss  = x.x * x.x + x.y * x.y + x.z * x.z + x.w * x.w;
#pragma unroll
        for (int o = 1; o < 64; o <<= 1) {
            dot += __shfl_xor(dot, o);
            ss  += __shfl_xor(ss, o);
        }
        if (lane == 0) {
            float cosv = dot / fmaxf(sqrtf(ss), 1e-12f);
            cosv = fminf(fmaxf(cosv, -1.f), 1.f);
            const float num = SCALE_F * cosf(acosf(cosv) + MARGIN_F);
            numv[b] = num;
            etv[b]  = __expf(SCALE_F * cosv);
        }
    }
}

// ---- kernel 2: main fused GEMM + exp row-sum ----
// Block = one 64-class slice, 8 waves (512 thr). Cooperative one-pass
// W-normalize into 32KB LDS (A-frags for 32x32x16), then each wave owns
// 8 sample-tiles of 32, barrier-free.
__global__ __launch_bounds__(512, 2) void k_main(const float* __restrict__ W,
                                                 const short* __restrict__ embF,
                                                 float* __restrict__ partial) {
    __shared__ short afrag_sh[2 * 16 * 64 * 8];   // 32 KB: [(ct*16+ks)*64+l]*8
    __shared__ float ssq_sh[8 * 64];              // 2 KB cross-wave norm
    const int tid  = threadIdx.x;
    const int lane = tid & 63;
    const int wv   = tid >> 6;    // wave id 0..7
    const int sl   = blockIdx.x;
    const int cbase = sl * 64;

    // ---- prologue: wave wv handles k-chunk [wv*32, +32) of ALL 64 rows;
    // lane = row. Loads are 128B/lane contiguous; LDS writes lane-contiguous.
    {
        const int c = cbase + lane;
        float v[32];
        if (c < Cn) {
            const float* wr = W + (size_t)c * Dn + wv * 32;
#pragma unroll
            for (int j = 0; j < 8; ++j) {
                float4 x = *(const float4*)(wr + j * 4);
                v[j * 4 + 0] = x.x; v[j * 4 + 1] = x.y;
                v[j * 4 + 2] = x.z; v[j * 4 + 3] = x.w;
            }
        } else {
#pragma unroll
            for (int j = 0; j < 32; ++j) v[j] = 0.0f;
        }
        float ss = 0.0f;
#pragma unroll
        for (int j = 0; j < 32; ++j) ss += v[j] * v[j];
        ssq_sh[wv * 64 + lane] = ss;
        __syncthreads();
        float tot = 0.0f;
#pragma unroll
        for (int w = 0; w < 8; ++w) tot += ssq_sh[w * 64 + lane];
        const float rn = 1.0f / fmaxf(sqrtf(tot), 1e-12f);
        // A layout (32x32x16): frag (ct,ks), lane l': row=ct*32+(l'&31),
        // k = ks*16 + (l'>>5)*8 + j. Here row=lane, k=wv*32+q2*8+j ->
        // ks = 2*wv + (q2>>1), h = q2&1, l' = h*32 + (lane&31).
        const int ct  = lane >> 5;
        const int r31 = lane & 31;
#pragma unroll
        for (int q2 = 0; q2 < 4; ++q2) {
            const int ks = 2 * wv + (q2 >> 1);
            const int h  = q2 & 1;
            bf16x8 a;
#pragma unroll
            for (int j = 0; j < 8; ++j) a[j] = f2bf_rne(v[q2 * 8 + j] * rn);
            *(bf16x8*)(afrag_sh + (size_t)((ct * 16 + ks) * 64 + h * 32 + r31) * 8) = a;
        }
    }
    __syncthreads();

    float* pout = partial + (size_t)sl * Bn;
    const bf16x8* bsrc = (const bf16x8*)embF;   // chunk-indexed (16B units)
    const int t0 = wv * NTW;                    // this wave's 8 sample tiles

    for (int i = 0; i < NTW; ++i) {
        const int t = t0 + i;
        const bf16x8* bp = bsrc + ((size_t)t << 10) + lane;
        bf16x8 bf[16];
#pragma unroll
        for (int ks = 0; ks < 16; ++ks) bf[ks] = bp[ks * 64];   // 1KB coalesced

        f32x16 a0 = {0.f,0.f,0.f,0.f,0.f,0.f,0.f,0.f,0.f,0.f,0.f,0.f,0.f,0.f,0.f,0.f};
        f32x16 a1 = {0.f,0.f,0.f,0.f,0.f,0.f,0.f,0.f,0.f,0.f,0.f,0.f,0.f,0.f,0.f,0.f};
#pragma unroll
        for (int ks = 0; ks < 16; ++ks) {
            const short* ap = afrag_sh + (size_t)(ks * 64 + lane) * 8;
            bf16x8 w0 = *(const bf16x8*)(ap);              // ct=0
            bf16x8 w1 = *(const bf16x8*)(ap + 16 * 64 * 8);// ct=1
            a0 = __builtin_amdgcn_mfma_f32_32x32x16_bf16(w0, bf[ks], a0, 0, 0, 0);
            a1 = __builtin_amdgcn_mfma_f32_32x32x16_bf16(w1, bf[ks], a1, 0, 0, 0);
        }
        // D layout (32x32): col=lane&31=sample; the 16 regs x 2 lane-halves
        // cover each class-row exactly once -> sum regs, then xor-32 merges
        // the complementary rows. d = 30*log2e*cos -> exp2 directly.
        float s0 = 0.f, s1 = 0.f, s2 = 0.f, s3 = 0.f;
#pragma unroll
        for (int r = 0; r < 16; r += 4) {
            s0 += __builtin_amdgcn_exp2f(a0[r + 0]);
            s1 += __builtin_amdgcn_exp2f(a0[r + 1]);
            s2 += __builtin_amdgcn_exp2f(a0[r + 2]);
            s3 += __builtin_amdgcn_exp2f(a0[r + 3]);
            s0 += __builtin_amdgcn_exp2f(a1[r + 0]);
            s1 += __builtin_amdgcn_exp2f(a1[r + 1]);
            s2 += __builtin_amdgcn_exp2f(a1[r + 2]);
            s3 += __builtin_amdgcn_exp2f(a1[r + 3]);
        }
        float s = (s0 + s1) + (s2 + s3);
        s += __shfl_xor(s, 32);                     // merge row-halves
        if (lane < 32) pout[t * 32 + lane] = s;     // 128B coalesced
    }
}

// ---- kernel 3: fused rowsum + loss ----
// 128 blocks x 256 thr; block owns 16 samples; tid = chunk*16 + l.
__global__ __launch_bounds__(256) void k_finish(const float* __restrict__ partial,
                                                const float* __restrict__ numv,
                                                const float* __restrict__ etv,
                                                float* __restrict__ out) {
    __shared__ float red[16];
    const int l     = threadIdx.x & 15;          // sample within block
    const int chunk = threadIdx.x >> 4;          // 0..15
    const int b  = blockIdx.x * 16 + l;

    if (threadIdx.x < 16) red[threadIdx.x] = 0.0f;
    __syncthreads();

    float acc = 0.0f;
    for (int s = chunk; s < NSLICE; s += 16) acc += partial[(size_t)s * Bn + b];
    // wave holds 4 chunks x 16 samples: fold chunks in-wave first
    acc += __shfl_xor(acc, 16);
    acc += __shfl_xor(acc, 32);
    if ((threadIdx.x & 63) < 16) atomicAdd(&red[l], acc);
    __syncthreads();

    if (threadIdx.x < 16) {
        const int bb = blockIdx.x * 16 + threadIdx.x;
        const float num  = numv[bb];
        const float excl = red[threadIdx.x] - OOB_COLS - etv[bb];  // drop pad + target
        float term = num - logf(__expf(num) + excl + EPS_F);
#pragma unroll
        for (int o = 1; o < 16; o <<= 1) term += __shfl_xor(term, o);
        if (threadIdx.x == 0) atomicAdd(out, -term / (float)Bn);
    }
}

extern "C" void kernel_launch(void* const* d_in, const int* in_sizes, int n_in,
                              void* d_out, int out_size, void* d_ws, size_t ws_size,
                              hipStream_t stream) {
    const float* emb = (const float*)d_in[0];   // 2048*256
    const float* W   = (const float*)d_in[1];   // 100000*256
    const int*   tgt = (const int*)d_in[2];     // 2048
    float* out = (float*)d_out;

    char* ws = (char*)d_ws;
    short* embF    = (short*)ws;                             // 1 MB (fragment order)
    float* partial = (float*)(ws + (1 << 20));               // 1564*2048*4 = 12.8 MB
    float* numv    = partial + (size_t)NSLICE * Bn;          // 8 KB
    float* etv     = numv + Bn;                              // 8 KB

    hipMemsetAsync(out, 0, sizeof(float), stream);
    k_prep<<<768, 256, 0, stream>>>(W, emb, tgt, embF, numv, etv);
    k_main<<<NSLICE, 512, 0, stream>>>(W, embF, partial);
    k_finish<<<128, 256, 0, stream>>>(partial, numv, etv, out);
}